// Round 14
// baseline (802.563 us; speedup 1.0000x reference)
//
#include <hip/hip_runtime.h>
#include <hip/hip_cooperative_groups.h>

namespace cg = cooperative_groups;

// ---------------------------------------------------------------------------
// MultimodalFusion, 5 dispatches (coop path):
//   pre1 (f2h x7 + abssum + hist-zero) -> projGEMM+part_kept (merged)
//   -> rpb_fused (hist x4 + finalize, ONE cooperative kernel, grid.sync)
//   -> hiddenGEMM -> finalGEMM
// GEMM = round-9-proven 128xBN tile, BK=32, 8 waves, double-buffered
// 1-barrier schedule + col-fastest XCD chunking. Fallback: 5-dispatch
// hist/finalize path if cooperative launch unsupported.
// ---------------------------------------------------------------------------

typedef _Float16 f16x8 __attribute__((ext_vector_type(8)));
typedef float f32x4 __attribute__((ext_vector_type(4)));

__device__ __forceinline__ unsigned short f16b(float v) {
  union { _Float16 h; unsigned short u; } cv; cv.h = (_Float16)v; return cv.u;
}

__device__ __forceinline__ void load_lds16(const void* g, void* l) {
  __builtin_amdgcn_global_load_lds(
      (const __attribute__((address_space(1))) void*)g,
      (__attribute__((address_space(3))) void*)l, 16, 0, 0);
}

__device__ __forceinline__ float sigmoidf_dev(float x) {
  return 1.0f / (1.0f + expf(-x));
}

#define NB_W1 768
#define NB_TOT 1024

// 256-lane-order region reduction (bit-identical across all kernels)
__device__ __forceinline__ float reduce_region_f(const float* part, int lo, int hi,
                                                 float* sbuf) {
  float a = 0.f;
  for (int i = lo + threadIdx.x; i < hi; i += 256) a += part[i];
  sbuf[threadIdx.x] = a; __syncthreads();
  for (int o = 128; o > 0; o >>= 1) {
    if ((int)threadIdx.x < o) sbuf[threadIdx.x] += sbuf[threadIdx.x + o];
    __syncthreads();
  }
  float r = sbuf[0];
  __syncthreads();
  return r;
}

// alpha = sum(kept |w|)/max(cnt,1) over pb/pc region (256-lane order)
__device__ __forceinline__ float alpha_region(const float* pb, const unsigned* pc,
                                              int lo, int hi, float* sf, unsigned* sc) {
  float a = 0.f; unsigned c = 0;
  for (int i = lo + threadIdx.x; i < hi; i += 256) { a += pb[i]; c += pc[i]; }
  sf[threadIdx.x] = a; sc[threadIdx.x] = c; __syncthreads();
  for (int o = 128; o > 0; o >>= 1) {
    if ((int)threadIdx.x < o) { sf[threadIdx.x] += sf[threadIdx.x + o]; sc[threadIdx.x] += sc[threadIdx.x + o]; }
    __syncthreads();
  }
  float s = sf[0]; float cnt = (float)sc[0];
  __syncthreads();
  if (cnt < 1.f) cnt = 1.f;
  return s / cnt;
}

// parallel radix chain over rounds [0, nr) of hists[round][w][256]; 256 threads.
__device__ __forceinline__ unsigned radix_prefix(const unsigned* __restrict__ hists,
                                                 int w, int nr, unsigned k,
                                                 unsigned* sscan, unsigned* res2) {
  int t = threadIdx.x;
  unsigned prefix = 0, krem = k;
  for (int rr = 0; rr < nr; ++rr) {
    sscan[t] = hists[(rr * 2 + w) * 256 + (255 - t)];
    __syncthreads();
#pragma unroll
    for (int o = 1; o < 256; o <<= 1) {
      unsigned add = (t >= o) ? sscan[t - o] : 0u;
      __syncthreads();
      sscan[t] += add;
      __syncthreads();
    }
    if (sscan[t] >= krem && (t == 0 || sscan[t - 1] < krem)) {
      res2[0] = (unsigned)(255 - t);
      res2[1] = (t == 0) ? 0u : sscan[t - 1];
    }
    __syncthreads();
    prefix |= res2[0] << (24 - 8 * rr);
    krem -= res2[1];
    __syncthreads();
  }
  return prefix;
}

// ---------------- pre1: batched f2h + abssum + hist-zero ---------------------
struct Pre1Args {
  const float* src[7];
  unsigned short* dst[7];
  long cum4[8];
  const float* W1; long n41;
  const float* W2; long n42;
  float* part;       // [NB_TOT]
  unsigned* hists;   // [4][2][256] zeroed by blocks 2048..2055
};

__global__ void pre1(Pre1Args a) {
  if (blockIdx.x < 2048) {
    long total = a.cum4[7];
    for (long i = (long)blockIdx.x * 256 + threadIdx.x; i < total;
         i += (long)2048 * 256) {
      int s = 0;
#pragma unroll
      for (int j = 1; j < 7; ++j) s += (i >= a.cum4[j]) ? 1 : 0;
      long off = i - a.cum4[s];
      float4 v = ((const float4*)a.src[s])[off];
      ushort4 o;
      o.x = f16b(v.x); o.y = f16b(v.y); o.z = f16b(v.z); o.w = f16b(v.w);
      ((ushort4*)a.dst[s])[off] = o;
    }
  } else {
    __shared__ float s[256];
    int bid2 = (int)blockIdx.x - 2048;
    if (bid2 < 8) a.hists[bid2 * 256 + threadIdx.x] = 0;
    int w = bid2 < NB_W1 ? 0 : 1;
    const float4* W4 = (const float4*)(w ? a.W2 : a.W1);
    long n4 = w ? a.n42 : a.n41;
    int nb = w ? (NB_TOT - NB_W1) : NB_W1;
    int bid = w ? bid2 - NB_W1 : bid2;
    float acc = 0.f;
    for (long i = (long)bid * 256 + threadIdx.x; i < n4;
         i += (long)nb * 256) {
      float4 v = W4[i];
      acc += fabsf(v.x) + fabsf(v.y) + fabsf(v.z) + fabsf(v.w);
    }
    s[threadIdx.x] = acc; __syncthreads();
    for (int o = 128; o > 0; o >>= 1) {
      if ((int)threadIdx.x < o) s[threadIdx.x] += s[threadIdx.x + o];
      __syncthreads();
    }
    if (threadIdx.x == 0) a.part[bid2] = s[0];
  }
}

// ---------------- shared args for hist/finalize ------------------------------
struct FinArgs {
  const float* Wq1; const float* Wq2; const float* Wf2;
  const float* bq2; const float* bf2; const float* mixp;
  const float* part; const float* pb; const unsigned* pc;
  unsigned* hists;
  unsigned k1, k2;
  unsigned short* wq1_h;  // 1024 x 3072
  unsigned short* w2_h;   // 1024 x 2048 ([mix*Wq2' | (1-mix)*Wf2])
  float* b2;              // 1024
};

// ---------------- finalize body (shared by fused + fallback) -----------------
__device__ __forceinline__ void finalize_body(const FinArgs& a,
                                              float d1, float a1, unsigned kth1,
                                              float d2, float a2, unsigned kth2) {
  const long S1 = 3145728, S2 = 1048576, D = 1024;
  float mix = sigmoidf_dev(a.mixp[0]);
  long total = S1 + 2 * S2 + D;
  for (long i = (long)blockIdx.x * blockDim.x + threadIdx.x; i < total;
       i += (long)gridDim.x * blockDim.x) {
    if (i < S1) {
      float x = a.Wq1[i];
      float wq = (fabsf(x) > d1) ? copysignf(a1, x) : 0.0f;
      float res = x - wq;
      float v = wq + ((__float_as_uint(fabsf(res)) >= kth1) ? res : 0.0f);
      a.wq1_h[i] = f16b(v);
    } else if (i < S1 + S2) {
      long j = i - S1; int r = (int)(j >> 10), c = (int)(j & 1023);
      float x = a.Wq2[j];
      float wq = (fabsf(x) > d2) ? copysignf(a2, x) : 0.0f;
      float res = x - wq;
      float v = wq + ((__float_as_uint(fabsf(res)) >= kth2) ? res : 0.0f);
      a.w2_h[(long)r * 2048 + c] = f16b(mix * v);
    } else if (i < S1 + 2 * S2) {
      long j = i - S1 - S2; int r = (int)(j >> 10), c = (int)(j & 1023);
      a.w2_h[(long)r * 2048 + 1024 + c] = f16b((1.0f - mix) * a.Wf2[j]);
    } else {
      long j = i - S1 - 2 * S2;
      a.b2[j] = mix * a.bq2[j] + (1.0f - mix) * a.bf2[j];
    }
  }
}

// ---------------- fused hist x4 + finalize (cooperative, grid.sync) ----------
__global__ void rpb_fused(FinArgs a) {
  cg::grid_group grid = cg::this_grid();
  __shared__ float sf[256]; __shared__ unsigned sc[256];
  __shared__ unsigned h[256]; __shared__ unsigned sscan[256];
  __shared__ unsigned res2[2];
  const long S1 = 3145728, S2 = 1048576;
  int t = threadIdx.x;
  int w = blockIdx.x < NB_W1 ? 0 : 1;
  const float* W = w ? a.Wq2 : a.Wq1;
  long S = w ? S2 : S1;
  int nb = w ? (NB_TOT - NB_W1) : NB_W1;
  int bid = w ? (int)blockIdx.x - NB_W1 : (int)blockIdx.x;
  int lo = w ? NB_W1 : 0, hi = w ? NB_TOT : NB_W1;
  float tot = reduce_region_f(a.part, lo, hi, sf);
  float delta = 0.7f * (tot / (float)S);
  float alpha = alpha_region(a.pb, a.pc, lo, hi, sf, sc);
  unsigned kw = w ? a.k2 : a.k1;
  for (int round = 0; round < 4; ++round) {
    unsigned prefix = radix_prefix(a.hists, w, round, kw, sscan, res2);
    h[t] = 0;
    __syncthreads();
    int shift = 24 - 8 * round;
    int hs = shift + 8;
    for (long i = (long)bid * 256 + t; i < S; i += (long)nb * 256) {
      float x = W[i];
      float aw = fabsf(x);
      float wq = (aw > delta) ? copysignf(alpha, x) : 0.0f;
      unsigned ub = __float_as_uint(fabsf(x - wq));
      bool ok = (hs >= 32) || ((ub >> hs) == (prefix >> hs));
      if (ok) atomicAdd(&h[(ub >> shift) & 255u], 1u);
    }
    __syncthreads();
    if (h[t]) atomicAdd(&a.hists[(round * 2 + w) * 256 + t], h[t]);
    grid.sync();
  }
  // finalize phase: all 1024 blocks recompute stats (parallel, bit-identical)
  float tot1 = reduce_region_f(a.part, 0, NB_W1, sf);
  float d1 = 0.7f * (tot1 / (float)S1);
  float tot2 = reduce_region_f(a.part, NB_W1, NB_TOT, sf);
  float d2 = 0.7f * (tot2 / (float)S2);
  float a1 = alpha_region(a.pb, a.pc, 0, NB_W1, sf, sc);
  float a2 = alpha_region(a.pb, a.pc, NB_W1, NB_TOT, sf, sc);
  unsigned kth1 = radix_prefix(a.hists, 0, 4, a.k1, sscan, res2);
  unsigned kth2 = radix_prefix(a.hists, 1, 4, a.k2, sscan, res2);
  finalize_body(a, d1, a1, kth1, d2, a2, kth2);
}

// ---------------- fallback: separate hist round + finalize -------------------
__global__ void hist_r(FinArgs a, int round) {
  __shared__ float sf[256]; __shared__ unsigned sc[256];
  __shared__ unsigned h[256]; __shared__ unsigned sscan[256];
  __shared__ unsigned res2[2];
  const long S1 = 3145728, S2 = 1048576;
  int t = threadIdx.x;
  int w = blockIdx.x < NB_W1 ? 0 : 1;
  const float* W = w ? a.Wq2 : a.Wq1;
  long S = w ? S2 : S1;
  int nb = w ? (NB_TOT - NB_W1) : NB_W1;
  int bid = w ? (int)blockIdx.x - NB_W1 : (int)blockIdx.x;
  int lo = w ? NB_W1 : 0, hi = w ? NB_TOT : NB_W1;
  float tot = reduce_region_f(a.part, lo, hi, sf);
  float delta = 0.7f * (tot / (float)S);
  float alpha = alpha_region(a.pb, a.pc, lo, hi, sf, sc);
  unsigned prefix = radix_prefix(a.hists, w, round, w ? a.k2 : a.k1, sscan, res2);
  h[t] = 0;
  __syncthreads();
  int shift = 24 - 8 * round;
  int hs = shift + 8;
  for (long i = (long)bid * 256 + t; i < S; i += (long)nb * 256) {
    float x = W[i];
    float aw = fabsf(x);
    float wq = (aw > delta) ? copysignf(alpha, x) : 0.0f;
    unsigned ub = __float_as_uint(fabsf(x - wq));
    bool ok = (hs >= 32) || ((ub >> hs) == (prefix >> hs));
    if (ok) atomicAdd(&h[(ub >> shift) & 255u], 1u);
  }
  __syncthreads();
  if (h[t]) atomicAdd(&a.hists[(round * 2 + w) * 256 + t], h[t]);
}

__global__ void finalize_weights(FinArgs a) {
  __shared__ float sf[256]; __shared__ unsigned sc[256];
  __shared__ unsigned sscan[256]; __shared__ unsigned res2[2];
  const long S1 = 3145728, S2 = 1048576;
  float tot1 = reduce_region_f(a.part, 0, NB_W1, sf);
  float d1 = 0.7f * (tot1 / (float)S1);
  float tot2 = reduce_region_f(a.part, NB_W1, NB_TOT, sf);
  float d2 = 0.7f * (tot2 / (float)S2);
  float a1 = alpha_region(a.pb, a.pc, 0, NB_W1, sf, sc);
  float a2 = alpha_region(a.pb, a.pc, NB_W1, NB_TOT, sf, sc);
  unsigned kth1 = radix_prefix(a.hists, 0, 4, a.k1, sscan, res2);
  unsigned kth2 = radix_prefix(a.hists, 1, 4, a.k2, sscan, res2);
  finalize_body(a, d1, a1, kth1, d2, a2, kth2);
}

// ---------------- fused GEMM (+ optional part_kept piggyback blocks) ---------
// Round-9-proven: 128xBN tile, BK=32, 8 waves (2x4), double-buffered LDS,
// ONE __syncthreads per K-tile, col-fastest XCD chunking.
struct GemmArgs {
  const unsigned short* A0; const unsigned short* A1; const unsigned short* A2;
  const unsigned short* B0; const unsigned short* B1; const unsigned short* B2;
  const float* c0; const float* c1; const float* c2;
  int K0, K1, K2;
  int nrows;   // grid rows = M / 128
  int ldc;     // output leading dim
  int cpsl;    // log2(col-blocks per operand set)
  int nwg;     // GEMM block count (multiple of 8)
  unsigned short* o0; unsigned short* o1; float* oF;
  // part_kept piggyback (PK=true only)
  const float* pkW1; long pkS1;
  const float* pkW2; long pkS2;
  const float* pkPart; float* pkPb; unsigned* pkPc;
};

template <int EPI, int BN, bool PK>
__global__ __launch_bounds__(512) void gemm9(GemmArgs g) {
  constexpr int AL = 128 * 32 * 2;   // 8 KB per A buffer
  constexpr int BL = BN * 32 * 2;    // 16 / 8 KB per B buffer
  constexpr int BISS = BL / 8192;    // B global_load_lds issues (2 / 1)
  constexpr int NR = BN / 4 / 16;    // per-wave N fragments (4 / 2)
  __shared__ __align__(16) char sm[2 * AL + 2 * BL];
  const int tid = threadIdx.x;

  if constexpr (PK) {
    if ((int)blockIdx.x >= g.nwg) {
      // ---- part_kept role: kept-|w| sum + count with per-block delta ----
      float* sf = (float*)sm;                   // 512 floats
      unsigned* sc = (unsigned*)(sm + 2048);    // 512 uints
      int bid2 = (int)blockIdx.x - g.nwg;       // 0..NB_TOT-1
      int w = bid2 < NB_W1 ? 0 : 1;
      const float* W = w ? g.pkW2 : g.pkW1;
      long S = w ? g.pkS2 : g.pkS1;
      int nb = w ? (NB_TOT - NB_W1) : NB_W1;
      int bid = w ? bid2 - NB_W1 : bid2;
      // delta recompute in strict 256-lane order (bit-identical to hist/fin)
      if (tid < 256) {
        float a = 0.f;
        for (int i = (w ? NB_W1 : 0) + tid; i < (w ? NB_TOT : NB_W1); i += 256)
          a += g.pkPart[i];
        sf[tid] = a;
      }
      __syncthreads();
      for (int o = 128; o > 0; o >>= 1) {
        if (tid < o) sf[tid] += sf[tid + o];
        __syncthreads();
      }
      float delta = 0.7f * (sf[0] / (float)S);
      __syncthreads();
      float a = 0.f; unsigned c = 0;
      for (long i = (long)bid * 512 + tid; i < S; i += (long)nb * 512) {
        float aw = fabsf(W[i]);
        if (aw > delta) { a += aw; ++c; }
      }
      sf[tid] = a; sc[tid] = c; __syncthreads();
      for (int o = 256; o > 0; o >>= 1) {
        if (tid < o) { sf[tid] += sf[tid + o]; sc[tid] += sc[tid + o]; }
        __syncthreads();
      }
      if (tid == 0) { g.pkPb[bid2] = sf[0]; g.pkPc[bid2] = sc[0]; }
      return;
    }
  }

  const int wid = tid >> 6;
  const int lane = tid & 63;
  const int wm = wid >> 2, wn = wid & 3;

  // bijective XCD-chunked swizzle (nwg % 8 == 0), col-fastest inside chunk
  const int nwg = g.nwg;
  const int id = (blockIdx.x & 7) * (nwg >> 3) + (blockIdx.x >> 3);
  const int ncols = nwg / g.nrows;
  const int c = id % ncols, r = id / ncols;
  const int sel = c >> g.cpsl, lc = c & ((1 << g.cpsl) - 1);

  const unsigned short* A = sel == 0 ? g.A0 : (sel == 1 ? g.A1 : g.A2);
  const unsigned short* Bw = sel == 0 ? g.B0 : (sel == 1 ? g.B1 : g.B2);
  const float* bias = sel == 0 ? g.c0 : (sel == 1 ? g.c1 : g.c2);
  const int K = sel == 0 ? g.K0 : (sel == 1 ? g.K1 : g.K2);
  const long brow = (long)r * 128;
  const int bRowB = lc * BN;

  f32x4 acc[4][NR];
#pragma unroll
  for (int i = 0; i < 4; ++i)
#pragma unroll
    for (int j = 0; j < NR; ++j)
#pragma unroll
      for (int e = 0; e < 4; ++e) acc[i][j][e] = 0.f;

  // staging: A tile 8KB = 1 issue/thread, B tile = BISS issues/thread
  const int oA = tid * 16;
  const unsigned short* aSrc = A + (brow + (oA >> 6)) * (long)K + ((oA & 63) >> 1);
  const unsigned short* bSrc[BISS];
#pragma unroll
  for (int j = 0; j < BISS; ++j) {
    int o = j * 8192 + tid * 16;
    bSrc[j] = Bw + (long)(bRowB + (o >> 6)) * K + ((o & 63) >> 1);
  }

  auto STAGE = [&](int buf, int k0) {
    load_lds16(aSrc + k0, sm + (size_t)buf * AL + wid * 1024);
#pragma unroll
    for (int j = 0; j < BISS; ++j)
      load_lds16(bSrc[j] + k0, sm + 2 * AL + (size_t)buf * BL + j * 8192 + wid * 1024);
  };

  const int kb = (lane >> 4) * 16;
  auto COMPUTE = [&](int buf) {
    const char* lAp = sm + (size_t)buf * AL;
    const char* lBp = sm + 2 * AL + (size_t)buf * BL;
    f16x8 a[4], b[NR];
#pragma unroll
    for (int m = 0; m < 4; ++m)
      a[m] = *(const f16x8*)(lAp + (wm * 64 + m * 16 + (lane & 15)) * 64 + kb);
#pragma unroll
    for (int n = 0; n < NR; ++n)
      b[n] = *(const f16x8*)(lBp + (wn * (BN / 4) + n * 16 + (lane & 15)) * 64 + kb);
#pragma unroll
    for (int m = 0; m < 4; ++m)
#pragma unroll
      for (int n = 0; n < NR; ++n)
        acc[m][n] = __builtin_amdgcn_mfma_f32_16x16x32_f16(a[m], b[n], acc[m][n], 0, 0, 0);
  };

  const int NT = K >> 5;
  STAGE(0, 0);
  __syncthreads();  // vmcnt(0) drain: tile 0 landed
  int cur = 0;
  for (int t = 0; t < NT - 1; ++t) {
    STAGE(cur ^ 1, (t + 1) << 5);  // prefetch next tile into other buffer
    COMPUTE(cur);
    __syncthreads();  // drains vmcnt+lgkmcnt: next tile ready, cur buf free
    cur ^= 1;
  }
  COMPUTE(cur);

  // epilogue: C row = (lane>>4)*4 + e, col = lane&15 (verified m89 layout)
  const int cb = c * BN + wn * (BN / 4);
  const int rb = r * 128 + wm * 64;
  const int bcol0 = bRowB + wn * (BN / 4);
#pragma unroll
  for (int i = 0; i < 4; ++i) {
    int r0 = rb + i * 16 + ((lane >> 4) << 2);
#pragma unroll
    for (int j = 0; j < NR; ++j) {
      int ccol = cb + j * 16 + (lane & 15);
      float bb = bias[bcol0 + j * 16 + (lane & 15)];
#pragma unroll
      for (int e = 0; e < 4; ++e) {
        float v = acc[i][j][e] + bb;
        long idx = (long)(r0 + e) * g.ldc + ccol;
        if constexpr (EPI == 0) {
          g.o0[idx] = f16b(v);
          g.o1[idx] = f16b(fabsf(v) >= 0.05f ? v : 0.0f);
        } else if constexpr (EPI == 1) {
          g.o0[idx] = f16b(fmaxf(v, 0.0f));
        } else {
          g.oF[idx] = v;
        }
      }
    }
  }
}

// ---------------------------------------------------------------------------
extern "C" void kernel_launch(void* const* d_in, const int* in_sizes, int n_in,
                              void* d_out, int out_size, void* d_ws, size_t ws_size,
                              hipStream_t stream) {
  const float* xv = (const float*)d_in[0];
  const float* xt = (const float*)d_in[1];
  const float* xa = (const float*)d_in[2];
  const float* Wv = (const float*)d_in[3];
  const float* bv = (const float*)d_in[4];
  const float* Wt = (const float*)d_in[5];
  const float* bt = (const float*)d_in[6];
  const float* Wa = (const float*)d_in[7];
  const float* ba = (const float*)d_in[8];
  const float* Wq1 = (const float*)d_in[9];
  const float* bq1 = (const float*)d_in[10];
  const float* Wq2 = (const float*)d_in[11];
  const float* bq2 = (const float*)d_in[12];
  const float* Wf1 = (const float*)d_in[13];
  const float* bf1 = (const float*)d_in[14];
  const float* Wf2 = (const float*)d_in[15];
  const float* bf2 = (const float*)d_in[16];
  const float* mixp = (const float*)d_in[17];

  const int B = 8192, D = 1024, T = 3072;
  const int Kv = 2048, Kt = 1024, Ka = 512;
  const long S1 = (long)D * T, S2 = (long)D * D;

  char* w = (char*)d_ws;
  auto alloc = [&](size_t bytes) -> char* {
    char* p = w; w += (bytes + 255) & ~(size_t)255; return p;
  };
  unsigned short* xv_h = (unsigned short*)alloc((size_t)B * Kv * 2);
  unsigned short* xt_h = (unsigned short*)alloc((size_t)B * Kt * 2);
  unsigned short* xa_h = (unsigned short*)alloc((size_t)B * Ka * 2);
  unsigned short* wv_h = (unsigned short*)alloc((size_t)D * Kv * 2);
  unsigned short* wt_h = (unsigned short*)alloc((size_t)D * Kt * 2);
  unsigned short* wa_h = (unsigned short*)alloc((size_t)D * Ka * 2);
  unsigned short* wq1_h = (unsigned short*)alloc((size_t)D * T * 2);
  unsigned short* wf1_h = (unsigned short*)alloc((size_t)D * T * 2);
  unsigned short* w2_h = (unsigned short*)alloc((size_t)D * 2048 * 2);
  unsigned short* concat_h = (unsigned short*)alloc((size_t)B * T * 2);
  unsigned short* routed_h = (unsigned short*)alloc((size_t)B * T * 2);
  unsigned short* a2_h = (unsigned short*)alloc((size_t)B * 2048 * 2);
  float* b2 = (float*)alloc(D * 4);
  float* part = (float*)alloc(1024 * 4);
  float* pb = (float*)alloc(1024 * 4);
  unsigned* pc = (unsigned*)alloc(1024 * 4);
  unsigned* hists = (unsigned*)alloc(4 * 2 * 256 * 4);  // [round][w][bin]

  const unsigned k1 = (unsigned)(S1 / 10), k2 = (unsigned)(S2 / 10);

  // ---- 1) pre1: f2h x7 + abssum + hist-zero ----
  Pre1Args pa;
  pa.src[0] = xv;  pa.dst[0] = xv_h;
  pa.src[1] = xt;  pa.dst[1] = xt_h;
  pa.src[2] = xa;  pa.dst[2] = xa_h;
  pa.src[3] = Wv;  pa.dst[3] = wv_h;
  pa.src[4] = Wt;  pa.dst[4] = wt_h;
  pa.src[5] = Wa;  pa.dst[5] = wa_h;
  pa.src[6] = Wf1; pa.dst[6] = wf1_h;
  long n4s[7] = {(long)B * Kv / 4, (long)B * Kt / 4, (long)B * Ka / 4,
                 (long)D * Kv / 4, (long)D * Kt / 4, (long)D * Ka / 4, S1 / 4};
  pa.cum4[0] = 0;
  for (int i = 0; i < 7; ++i) pa.cum4[i + 1] = pa.cum4[i] + n4s[i];
  pa.W1 = Wq1; pa.n41 = S1 / 4;
  pa.W2 = Wq2; pa.n42 = S2 / 4;
  pa.part = part; pa.hists = hists;
  pre1<<<3072, 256, 0, stream>>>(pa);

  // ---- 2) proj GEMM (768 blocks) + part_kept (1024 blocks), merged ----
  GemmArgs gp;
  gp.A0 = xv_h; gp.A1 = xt_h; gp.A2 = xa_h;
  gp.B0 = wv_h; gp.B1 = wt_h; gp.B2 = wa_h;
  gp.c0 = bv; gp.c1 = bt; gp.c2 = ba;
  gp.K0 = Kv; gp.K1 = Kt; gp.K2 = Ka;
  gp.nrows = B / 128; gp.ldc = T; gp.cpsl = 2; gp.nwg = 12 * (B / 128);
  gp.o0 = concat_h; gp.o1 = routed_h; gp.oF = nullptr;
  gp.pkW1 = Wq1; gp.pkS1 = S1;
  gp.pkW2 = Wq2; gp.pkS2 = S2;
  gp.pkPart = part; gp.pkPb = pb; gp.pkPc = pc;
  gemm9<0, 256, true><<<gp.nwg + NB_TOT, 512, 0, stream>>>(gp);

  // ---- 3) fused radix select + finalize (cooperative; fallback = 5 disp) ----
  FinArgs fw;
  fw.Wq1 = Wq1; fw.Wq2 = Wq2; fw.Wf2 = Wf2;
  fw.bq2 = bq2; fw.bf2 = bf2; fw.mixp = mixp;
  fw.part = part; fw.pb = pb; fw.pc = pc; fw.hists = hists;
  fw.k1 = k1; fw.k2 = k2;
  fw.wq1_h = wq1_h; fw.w2_h = w2_h; fw.b2 = b2;
  {
    void* kargs[] = { (void*)&fw };
    hipError_t ce = hipLaunchCooperativeKernel((void*)rpb_fused, dim3(NB_TOT),
                                               dim3(256), kargs, 0, stream);
    if (ce != hipSuccess) {
      (void)hipGetLastError();  // clear sticky error; use proven fallback
      for (int rr = 0; rr < 4; ++rr)
        hist_r<<<NB_TOT, 256, 0, stream>>>(fw, rr);
      finalize_weights<<<1024, 256, 0, stream>>>(fw);
    }
  }

  // ---- 4) hidden GEMM: A2 = [h | g], N = 2048, BN=256 ----
  GemmArgs gh;
  gh.A0 = routed_h; gh.A1 = concat_h; gh.A2 = routed_h;
  gh.B0 = wq1_h; gh.B1 = wf1_h; gh.B2 = wq1_h;
  gh.c0 = bq1; gh.c1 = bf1; gh.c2 = bq1;
  gh.K0 = T; gh.K1 = T; gh.K2 = T;
  gh.nrows = B / 128; gh.ldc = 2048; gh.cpsl = 2; gh.nwg = 8 * (B / 128);
  gh.o0 = a2_h; gh.o1 = nullptr; gh.oF = nullptr;
  gemm9<1, 256, false><<<gh.nwg, 512, 0, stream>>>(gh);

  // ---- 5) final GEMM: N = 1024, BN=128 ----
  GemmArgs gf;
  gf.A0 = a2_h; gf.A1 = a2_h; gf.A2 = a2_h;
  gf.B0 = w2_h; gf.B1 = w2_h; gf.B2 = w2_h;
  gf.c0 = b2; gf.c1 = b2; gf.c2 = b2;
  gf.K0 = 2048; gf.K1 = 2048; gf.K2 = 2048;
  gf.nrows = B / 128; gf.ldc = D; gf.cpsl = 3; gf.nwg = 8 * (B / 128);
  gf.o0 = nullptr; gf.o1 = nullptr; gf.oF = (float*)d_out;
  gemm9<2, 128, false><<<gf.nwg, 512, 0, stream>>>(gf);
}

// Round 15
// 390.900 us; speedup vs baseline: 2.0531x; 2.0531x over previous
//
#include <hip/hip_runtime.h>

// ---------------------------------------------------------------------------
// MultimodalFusion, 9 dispatches total (round-9 proven configuration):
//   pre1 (f2h x7 + abssum + hist-zero)  ->  projGEMM+part_kept (merged)
//   -> hist x4 (sel merged in-block)    ->  finalize  -> hiddenGEMM -> finalGEMM
// GEMM K-loop = proven 128xBN tile, BK=32, 8 waves, double-buffered
// 1-barrier schedule + col-fastest XCD chunking.
// ---------------------------------------------------------------------------

typedef _Float16 f16x8 __attribute__((ext_vector_type(8)));
typedef float f32x4 __attribute__((ext_vector_type(4)));

__device__ __forceinline__ unsigned short f16b(float v) {
  union { _Float16 h; unsigned short u; } cv; cv.h = (_Float16)v; return cv.u;
}

__device__ __forceinline__ void load_lds16(const void* g, void* l) {
  __builtin_amdgcn_global_load_lds(
      (const __attribute__((address_space(1))) void*)g,
      (__attribute__((address_space(3))) void*)l, 16, 0, 0);
}

__device__ __forceinline__ float sigmoidf_dev(float x) {
  return 1.0f / (1.0f + expf(-x));
}

#define NB_W1 768
#define NB_TOT 1024

// 256-lane-order region reduction (bit-identical across all kernels)
__device__ __forceinline__ float reduce_region_f(const float* part, int lo, int hi,
                                                 float* sbuf) {
  float a = 0.f;
  for (int i = lo + threadIdx.x; i < hi; i += 256) a += part[i];
  sbuf[threadIdx.x] = a; __syncthreads();
  for (int o = 128; o > 0; o >>= 1) {
    if ((int)threadIdx.x < o) sbuf[threadIdx.x] += sbuf[threadIdx.x + o];
    __syncthreads();
  }
  float r = sbuf[0];
  __syncthreads();
  return r;
}

// alpha = sum(kept |w|)/max(cnt,1) over pb/pc region (256-lane order)
__device__ __forceinline__ float alpha_region(const float* pb, const unsigned* pc,
                                              int lo, int hi, float* sf, unsigned* sc) {
  float a = 0.f; unsigned c = 0;
  for (int i = lo + threadIdx.x; i < hi; i += 256) { a += pb[i]; c += pc[i]; }
  sf[threadIdx.x] = a; sc[threadIdx.x] = c; __syncthreads();
  for (int o = 128; o > 0; o >>= 1) {
    if ((int)threadIdx.x < o) { sf[threadIdx.x] += sf[threadIdx.x + o]; sc[threadIdx.x] += sc[threadIdx.x + o]; }
    __syncthreads();
  }
  float s = sf[0]; float cnt = (float)sc[0];
  __syncthreads();
  if (cnt < 1.f) cnt = 1.f;
  return s / cnt;
}

// parallel radix chain over rounds [0, nr) of hists[round][w][256]; 256 threads.
// Integer-exact; equivalent to serial scan from bin 255 down.
__device__ __forceinline__ unsigned radix_prefix(const unsigned* __restrict__ hists,
                                                 int w, int nr, unsigned k,
                                                 unsigned* sscan, unsigned* res2) {
  int t = threadIdx.x;
  unsigned prefix = 0, krem = k;
  for (int rr = 0; rr < nr; ++rr) {
    sscan[t] = hists[(rr * 2 + w) * 256 + (255 - t)];
    __syncthreads();
#pragma unroll
    for (int o = 1; o < 256; o <<= 1) {
      unsigned add = (t >= o) ? sscan[t - o] : 0u;
      __syncthreads();
      sscan[t] += add;
      __syncthreads();
    }
    // sscan[t] = suffix(255-t); want largest b with suffix(b)>=krem
    if (sscan[t] >= krem && (t == 0 || sscan[t - 1] < krem)) {
      res2[0] = (unsigned)(255 - t);
      res2[1] = (t == 0) ? 0u : sscan[t - 1];  // above = suffix(b+1)
    }
    __syncthreads();
    prefix |= res2[0] << (24 - 8 * rr);
    krem -= res2[1];
    __syncthreads();
  }
  return prefix;
}

// ---------------- pre1: batched f2h + abssum + hist-zero ---------------------
struct Pre1Args {
  const float* src[7];
  unsigned short* dst[7];
  long cum4[8];
  const float* W1; long n41;
  const float* W2; long n42;
  float* part;       // [NB_TOT]
  unsigned* hists;   // [4][2][256] zeroed by blocks 2048..2055
};

__global__ void pre1(Pre1Args a) {
  if (blockIdx.x < 2048) {
    long total = a.cum4[7];
    for (long i = (long)blockIdx.x * 256 + threadIdx.x; i < total;
         i += (long)2048 * 256) {
      int s = 0;
#pragma unroll
      for (int j = 1; j < 7; ++j) s += (i >= a.cum4[j]) ? 1 : 0;
      long off = i - a.cum4[s];
      float4 v = ((const float4*)a.src[s])[off];
      ushort4 o;
      o.x = f16b(v.x); o.y = f16b(v.y); o.z = f16b(v.z); o.w = f16b(v.w);
      ((ushort4*)a.dst[s])[off] = o;
    }
  } else {
    __shared__ float s[256];
    int bid2 = (int)blockIdx.x - 2048;
    if (bid2 < 8) a.hists[bid2 * 256 + threadIdx.x] = 0;
    int w = bid2 < NB_W1 ? 0 : 1;
    const float4* W4 = (const float4*)(w ? a.W2 : a.W1);
    long n4 = w ? a.n42 : a.n41;
    int nb = w ? (NB_TOT - NB_W1) : NB_W1;
    int bid = w ? bid2 - NB_W1 : bid2;
    float acc = 0.f;
    for (long i = (long)bid * 256 + threadIdx.x; i < n4;
         i += (long)nb * 256) {
      float4 v = W4[i];
      acc += fabsf(v.x) + fabsf(v.y) + fabsf(v.z) + fabsf(v.w);
    }
    s[threadIdx.x] = acc; __syncthreads();
    for (int o = 128; o > 0; o >>= 1) {
      if ((int)threadIdx.x < o) s[threadIdx.x] += s[threadIdx.x + o];
      __syncthreads();
    }
    if (threadIdx.x == 0) a.part[bid2] = s[0];
  }
}

// ---------------- radix histogram round (prefix chain recomputed in-block) ---
__global__ void hist_r(const float* __restrict__ W1, long S1v,
                       const float* __restrict__ W2, long S2v,
                       const float* __restrict__ part,
                       const float* __restrict__ pb, const unsigned* __restrict__ pc,
                       unsigned* __restrict__ hists, int round,
                       unsigned k1, unsigned k2) {
  __shared__ float sf[256]; __shared__ unsigned sc[256];
  __shared__ unsigned h[256]; __shared__ unsigned sscan[256];
  __shared__ unsigned res2[2];
  int t = threadIdx.x;
  int w = blockIdx.x < NB_W1 ? 0 : 1;
  const float* W = w ? W2 : W1;
  long S = w ? S2v : S1v;
  int nb = w ? (NB_TOT - NB_W1) : NB_W1;
  int bid = w ? (int)blockIdx.x - NB_W1 : (int)blockIdx.x;
  int lo = w ? NB_W1 : 0, hi = w ? NB_TOT : NB_W1;
  float tot = reduce_region_f(part, lo, hi, sf);
  float delta = 0.7f * (tot / (float)S);
  float alpha = alpha_region(pb, pc, lo, hi, sf, sc);
  unsigned prefix = radix_prefix(hists, w, round, w ? k2 : k1, sscan, res2);
  h[t] = 0;
  __syncthreads();
  int shift = 24 - 8 * round;
  int hs = shift + 8;
  for (long i = (long)bid * 256 + t; i < S; i += (long)nb * 256) {
    float x = W[i];
    float aw = fabsf(x);
    float wq = (aw > delta) ? copysignf(alpha, x) : 0.0f;
    unsigned ub = __float_as_uint(fabsf(x - wq));
    bool ok = (hs >= 32) || ((ub >> hs) == (prefix >> hs));
    if (ok) atomicAdd(&h[(ub >> shift) & 255u], 1u);
  }
  __syncthreads();
  if (h[t]) atomicAdd(&hists[(round * 2 + w) * 256 + t], h[t]);
}

// ---------------- fused weight finalize (recomputes all stats in-block) ------
struct FinArgs {
  const float* Wq1; const float* Wq2; const float* Wf2;
  const float* bq2; const float* bf2; const float* mixp;
  const float* part; const float* pb; const unsigned* pc;
  const unsigned* hists;
  unsigned k1, k2;
  unsigned short* wq1_h;  // 1024 x 3072
  unsigned short* w2_h;   // 1024 x 2048 ([mix*Wq2' | (1-mix)*Wf2])
  float* b2;              // 1024
};

__global__ void finalize_weights(FinArgs a) {
  __shared__ float sf[256]; __shared__ unsigned sc[256];
  __shared__ unsigned sscan[256]; __shared__ unsigned res2[2];
  const long S1 = 3145728, S2 = 1048576, D = 1024;
  float tot1 = reduce_region_f(a.part, 0, NB_W1, sf);
  float d1 = 0.7f * (tot1 / (float)S1);
  float tot2 = reduce_region_f(a.part, NB_W1, NB_TOT, sf);
  float d2 = 0.7f * (tot2 / (float)S2);
  float a1 = alpha_region(a.pb, a.pc, 0, NB_W1, sf, sc);
  float a2 = alpha_region(a.pb, a.pc, NB_W1, NB_TOT, sf, sc);
  unsigned kth1 = radix_prefix(a.hists, 0, 4, a.k1, sscan, res2);
  unsigned kth2 = radix_prefix(a.hists, 1, 4, a.k2, sscan, res2);
  float mix = sigmoidf_dev(a.mixp[0]);
  long total = S1 + 2 * S2 + D;
  for (long i = (long)blockIdx.x * blockDim.x + threadIdx.x; i < total;
       i += (long)gridDim.x * blockDim.x) {
    if (i < S1) {
      float x = a.Wq1[i];
      float wq = (fabsf(x) > d1) ? copysignf(a1, x) : 0.0f;
      float res = x - wq;
      float v = wq + ((__float_as_uint(fabsf(res)) >= kth1) ? res : 0.0f);
      a.wq1_h[i] = f16b(v);
    } else if (i < S1 + S2) {
      long j = i - S1; int r = (int)(j >> 10), c = (int)(j & 1023);
      float x = a.Wq2[j];
      float wq = (fabsf(x) > d2) ? copysignf(a2, x) : 0.0f;
      float res = x - wq;
      float v = wq + ((__float_as_uint(fabsf(res)) >= kth2) ? res : 0.0f);
      a.w2_h[(long)r * 2048 + c] = f16b(mix * v);
    } else if (i < S1 + 2 * S2) {
      long j = i - S1 - S2; int r = (int)(j >> 10), c = (int)(j & 1023);
      a.w2_h[(long)r * 2048 + 1024 + c] = f16b((1.0f - mix) * a.Wf2[j]);
    } else {
      long j = i - S1 - 2 * S2;
      a.b2[j] = mix * a.bq2[j] + (1.0f - mix) * a.bf2[j];
    }
  }
}

// ---------------- fused GEMM (+ optional part_kept piggyback blocks) ---------
// C[M, sel-cols] = A_sel[M, K_sel] @ B_sel[BN-slice, K_sel]^T + bias_sel
// 512 threads = 8 waves (2x4), per-wave 64 x BN/4. Double-buffered LDS,
// ONE __syncthreads per K-tile (proven schedule). Col-fastest XCD
// chunking over the first nwg blocks; blocks >= nwg run part_kept role.
struct GemmArgs {
  const unsigned short* A0; const unsigned short* A1; const unsigned short* A2;
  const unsigned short* B0; const unsigned short* B1; const unsigned short* B2;
  const float* c0; const float* c1; const float* c2;
  int K0, K1, K2;
  int nrows;   // grid rows = M / 128
  int ldc;     // output leading dim
  int cpsl;    // log2(col-blocks per operand set)
  int nwg;     // GEMM block count (multiple of 8)
  unsigned short* o0; unsigned short* o1; float* oF;
  // part_kept piggyback (PK=true only)
  const float* pkW1; long pkS1;
  const float* pkW2; long pkS2;
  const float* pkPart; float* pkPb; unsigned* pkPc;
};

template <int EPI, int BN, bool PK>
__global__ __launch_bounds__(512) void gemm9(GemmArgs g) {
  constexpr int AL = 128 * 32 * 2;   // 8 KB per A buffer
  constexpr int BL = BN * 32 * 2;    // 16 / 8 KB per B buffer
  constexpr int BISS = BL / 8192;    // B global_load_lds issues (2 / 1)
  constexpr int NR = BN / 4 / 16;    // per-wave N fragments (4 / 2)
  __shared__ __align__(16) char sm[2 * AL + 2 * BL];
  const int tid = threadIdx.x;

  if constexpr (PK) {
    if ((int)blockIdx.x >= g.nwg) {
      // ---- part_kept role: kept-|w| sum + count with per-block delta ----
      float* sf = (float*)sm;                   // 512 floats
      unsigned* sc = (unsigned*)(sm + 2048);    // 512 uints
      int bid2 = (int)blockIdx.x - g.nwg;       // 0..NB_TOT-1
      int w = bid2 < NB_W1 ? 0 : 1;
      const float* W = w ? g.pkW2 : g.pkW1;
      long S = w ? g.pkS2 : g.pkS1;
      int nb = w ? (NB_TOT - NB_W1) : NB_W1;
      int bid = w ? bid2 - NB_W1 : bid2;
      // delta recompute in strict 256-lane order (bit-identical to hist/fin)
      if (tid < 256) {
        float a = 0.f;
        for (int i = (w ? NB_W1 : 0) + tid; i < (w ? NB_TOT : NB_W1); i += 256)
          a += g.pkPart[i];
        sf[tid] = a;
      }
      __syncthreads();
      for (int o = 128; o > 0; o >>= 1) {
        if (tid < o) sf[tid] += sf[tid + o];
        __syncthreads();
      }
      float delta = 0.7f * (sf[0] / (float)S);
      __syncthreads();
      float a = 0.f; unsigned c = 0;
      for (long i = (long)bid * 512 + tid; i < S; i += (long)nb * 512) {
        float aw = fabsf(W[i]);
        if (aw > delta) { a += aw; ++c; }
      }
      sf[tid] = a; sc[tid] = c; __syncthreads();
      for (int o = 256; o > 0; o >>= 1) {
        if (tid < o) { sf[tid] += sf[tid + o]; sc[tid] += sc[tid + o]; }
        __syncthreads();
      }
      if (tid == 0) { g.pkPb[bid2] = sf[0]; g.pkPc[bid2] = sc[0]; }
      return;
    }
  }

  const int wid = tid >> 6;
  const int lane = tid & 63;
  const int wm = wid >> 2, wn = wid & 3;

  // bijective XCD-chunked swizzle (nwg % 8 == 0), col-fastest inside chunk
  const int nwg = g.nwg;
  const int id = (blockIdx.x & 7) * (nwg >> 3) + (blockIdx.x >> 3);
  const int ncols = nwg / g.nrows;
  const int c = id % ncols, r = id / ncols;
  const int sel = c >> g.cpsl, lc = c & ((1 << g.cpsl) - 1);

  const unsigned short* A = sel == 0 ? g.A0 : (sel == 1 ? g.A1 : g.A2);
  const unsigned short* Bw = sel == 0 ? g.B0 : (sel == 1 ? g.B1 : g.B2);
  const float* bias = sel == 0 ? g.c0 : (sel == 1 ? g.c1 : g.c2);
  const int K = sel == 0 ? g.K0 : (sel == 1 ? g.K1 : g.K2);
  const long brow = (long)r * 128;
  const int bRowB = lc * BN;

  f32x4 acc[4][NR];
#pragma unroll
  for (int i = 0; i < 4; ++i)
#pragma unroll
    for (int j = 0; j < NR; ++j)
#pragma unroll
      for (int e = 0; e < 4; ++e) acc[i][j][e] = 0.f;

  // staging: A tile 8KB = 1 issue/thread, B tile = BISS issues/thread
  const int oA = tid * 16;
  const unsigned short* aSrc = A + (brow + (oA >> 6)) * (long)K + ((oA & 63) >> 1);
  const unsigned short* bSrc[BISS];
#pragma unroll
  for (int j = 0; j < BISS; ++j) {
    int o = j * 8192 + tid * 16;
    bSrc[j] = Bw + (long)(bRowB + (o >> 6)) * K + ((o & 63) >> 1);
  }

  auto STAGE = [&](int buf, int k0) {
    load_lds16(aSrc + k0, sm + (size_t)buf * AL + wid * 1024);
#pragma unroll
    for (int j = 0; j < BISS; ++j)
      load_lds16(bSrc[j] + k0, sm + 2 * AL + (size_t)buf * BL + j * 8192 + wid * 1024);
  };

  const int kb = (lane >> 4) * 16;
  auto COMPUTE = [&](int buf) {
    const char* lAp = sm + (size_t)buf * AL;
    const char* lBp = sm + 2 * AL + (size_t)buf * BL;
    f16x8 a[4], b[NR];
#pragma unroll
    for (int m = 0; m < 4; ++m)
      a[m] = *(const f16x8*)(lAp + (wm * 64 + m * 16 + (lane & 15)) * 64 + kb);
#pragma unroll
    for (int n = 0; n < NR; ++n)
      b[n] = *(const f16x8*)(lBp + (wn * (BN / 4) + n * 16 + (lane & 15)) * 64 + kb);
#pragma unroll
    for (int m = 0; m < 4; ++m)
#pragma unroll
      for (int n = 0; n < NR; ++n)
        acc[m][n] = __builtin_amdgcn_mfma_f32_16x16x32_f16(a[m], b[n], acc[m][n], 0, 0, 0);
  };

  const int NT = K >> 5;
  STAGE(0, 0);
  __syncthreads();  // vmcnt(0) drain: tile 0 landed
  int cur = 0;
  for (int t = 0; t < NT - 1; ++t) {
    STAGE(cur ^ 1, (t + 1) << 5);  // prefetch next tile into other buffer
    COMPUTE(cur);
    __syncthreads();  // drains vmcnt+lgkmcnt: next tile ready, cur buf free
    cur ^= 1;
  }
  COMPUTE(cur);

  // epilogue: C row = (lane>>4)*4 + e, col = lane&15 (verified m89 layout)
  const int cb = c * BN + wn * (BN / 4);
  const int rb = r * 128 + wm * 64;
  const int bcol0 = bRowB + wn * (BN / 4);
#pragma unroll
  for (int i = 0; i < 4; ++i) {
    int r0 = rb + i * 16 + ((lane >> 4) << 2);
#pragma unroll
    for (int j = 0; j < NR; ++j) {
      int ccol = cb + j * 16 + (lane & 15);
      float bb = bias[bcol0 + j * 16 + (lane & 15)];
#pragma unroll
      for (int e = 0; e < 4; ++e) {
        float v = acc[i][j][e] + bb;
        long idx = (long)(r0 + e) * g.ldc + ccol;
        if constexpr (EPI == 0) {
          g.o0[idx] = f16b(v);
          g.o1[idx] = f16b(fabsf(v) >= 0.05f ? v : 0.0f);
        } else if constexpr (EPI == 1) {
          g.o0[idx] = f16b(fmaxf(v, 0.0f));
        } else {
          g.oF[idx] = v;
        }
      }
    }
  }
}

// ---------------------------------------------------------------------------
extern "C" void kernel_launch(void* const* d_in, const int* in_sizes, int n_in,
                              void* d_out, int out_size, void* d_ws, size_t ws_size,
                              hipStream_t stream) {
  const float* xv = (const float*)d_in[0];
  const float* xt = (const float*)d_in[1];
  const float* xa = (const float*)d_in[2];
  const float* Wv = (const float*)d_in[3];
  const float* bv = (const float*)d_in[4];
  const float* Wt = (const float*)d_in[5];
  const float* bt = (const float*)d_in[6];
  const float* Wa = (const float*)d_in[7];
  const float* ba = (const float*)d_in[8];
  const float* Wq1 = (const float*)d_in[9];
  const float* bq1 = (const float*)d_in[10];
  const float* Wq2 = (const float*)d_in[11];
  const float* bq2 = (const float*)d_in[12];
  const float* Wf1 = (const float*)d_in[13];
  const float* bf1 = (const float*)d_in[14];
  const float* Wf2 = (const float*)d_in[15];
  const float* bf2 = (const float*)d_in[16];
  const float* mixp = (const float*)d_in[17];

  const int B = 8192, D = 1024, T = 3072;
  const int Kv = 2048, Kt = 1024, Ka = 512;
  const long S1 = (long)D * T, S2 = (long)D * D;

  char* w = (char*)d_ws;
  auto alloc = [&](size_t bytes) -> char* {
    char* p = w; w += (bytes + 255) & ~(size_t)255; return p;
  };
  unsigned short* xv_h = (unsigned short*)alloc((size_t)B * Kv * 2);
  unsigned short* xt_h = (unsigned short*)alloc((size_t)B * Kt * 2);
  unsigned short* xa_h = (unsigned short*)alloc((size_t)B * Ka * 2);
  unsigned short* wv_h = (unsigned short*)alloc((size_t)D * Kv * 2);
  unsigned short* wt_h = (unsigned short*)alloc((size_t)D * Kt * 2);
  unsigned short* wa_h = (unsigned short*)alloc((size_t)D * Ka * 2);
  unsigned short* wq1_h = (unsigned short*)alloc((size_t)D * T * 2);
  unsigned short* wf1_h = (unsigned short*)alloc((size_t)D * T * 2);
  unsigned short* w2_h = (unsigned short*)alloc((size_t)D * 2048 * 2);
  unsigned short* concat_h = (unsigned short*)alloc((size_t)B * T * 2);
  unsigned short* routed_h = (unsigned short*)alloc((size_t)B * T * 2);
  unsigned short* a2_h = (unsigned short*)alloc((size_t)B * 2048 * 2);
  float* b2 = (float*)alloc(D * 4);
  float* part = (float*)alloc(1024 * 4);
  float* pb = (float*)alloc(1024 * 4);
  unsigned* pc = (unsigned*)alloc(1024 * 4);
  unsigned* hists = (unsigned*)alloc(4 * 2 * 256 * 4);  // [round][w][bin]

  const unsigned k1 = (unsigned)(S1 / 10), k2 = (unsigned)(S2 / 10);

  // ---- 1) pre1: f2h x7 + abssum + hist-zero ----
  Pre1Args pa;
  pa.src[0] = xv;  pa.dst[0] = xv_h;
  pa.src[1] = xt;  pa.dst[1] = xt_h;
  pa.src[2] = xa;  pa.dst[2] = xa_h;
  pa.src[3] = Wv;  pa.dst[3] = wv_h;
  pa.src[4] = Wt;  pa.dst[4] = wt_h;
  pa.src[5] = Wa;  pa.dst[5] = wa_h;
  pa.src[6] = Wf1; pa.dst[6] = wf1_h;
  long n4s[7] = {(long)B * Kv / 4, (long)B * Kt / 4, (long)B * Ka / 4,
                 (long)D * Kv / 4, (long)D * Kt / 4, (long)D * Ka / 4, S1 / 4};
  pa.cum4[0] = 0;
  for (int i = 0; i < 7; ++i) pa.cum4[i + 1] = pa.cum4[i] + n4s[i];
  pa.W1 = Wq1; pa.n41 = S1 / 4;
  pa.W2 = Wq2; pa.n42 = S2 / 4;
  pa.part = part; pa.hists = hists;
  pre1<<<3072, 256, 0, stream>>>(pa);

  // ---- 2) proj GEMM (768 blocks) + part_kept (1024 blocks), merged ----
  GemmArgs gp;
  gp.A0 = xv_h; gp.A1 = xt_h; gp.A2 = xa_h;
  gp.B0 = wv_h; gp.B1 = wt_h; gp.B2 = wa_h;
  gp.c0 = bv; gp.c1 = bt; gp.c2 = ba;
  gp.K0 = Kv; gp.K1 = Kt; gp.K2 = Ka;
  gp.nrows = B / 128; gp.ldc = T; gp.cpsl = 2; gp.nwg = 12 * (B / 128);
  gp.o0 = concat_h; gp.o1 = routed_h; gp.oF = nullptr;
  gp.pkW1 = Wq1; gp.pkS1 = S1;
  gp.pkW2 = Wq2; gp.pkS2 = S2;
  gp.pkPart = part; gp.pkPb = pb; gp.pkPc = pc;
  gemm9<0, 256, true><<<gp.nwg + NB_TOT, 512, 0, stream>>>(gp);

  // ---- 3-6) radix hist rounds (sel merged in-block) ----
  for (int rr = 0; rr < 4; ++rr)
    hist_r<<<NB_TOT, 256, 0, stream>>>(Wq1, S1, Wq2, S2, part, pb, pc,
                                       hists, rr, k1, k2);

  // ---- 7) fused weight finalize ----
  FinArgs fw;
  fw.Wq1 = Wq1; fw.Wq2 = Wq2; fw.Wf2 = Wf2;
  fw.bq2 = bq2; fw.bf2 = bf2; fw.mixp = mixp;
  fw.part = part; fw.pb = pb; fw.pc = pc; fw.hists = hists;
  fw.k1 = k1; fw.k2 = k2;
  fw.wq1_h = wq1_h; fw.w2_h = w2_h; fw.b2 = b2;
  finalize_weights<<<1024, 256, 0, stream>>>(fw);

  // ---- 8) hidden GEMM: A2 = [h | g], N = 2048, BN=256 ----
  GemmArgs gh;
  gh.A0 = routed_h; gh.A1 = concat_h; gh.A2 = routed_h;
  gh.B0 = wq1_h; gh.B1 = wf1_h; gh.B2 = wq1_h;
  gh.c0 = bq1; gh.c1 = bf1; gh.c2 = bq1;
  gh.K0 = T; gh.K1 = T; gh.K2 = T;
  gh.nrows = B / 128; gh.ldc = 2048; gh.cpsl = 2; gh.nwg = 8 * (B / 128);
  gh.o0 = a2_h; gh.o1 = nullptr; gh.oF = nullptr;
  gemm9<1, 256, false><<<gh.nwg, 512, 0, stream>>>(gh);

  // ---- 9) final GEMM: N = 1024, BN=128 ----
  GemmArgs gf;
  gf.A0 = a2_h; gf.A1 = a2_h; gf.A2 = a2_h;
  gf.B0 = w2_h; gf.B1 = w2_h; gf.B2 = w2_h;
  gf.c0 = b2; gf.c1 = b2; gf.c2 = b2;
  gf.K0 = 2048; gf.K1 = 2048; gf.K2 = 2048;
  gf.nrows = B / 128; gf.ldc = D; gf.cpsl = 3; gf.nwg = 8 * (B / 128);
  gf.o0 = nullptr; gf.o1 = nullptr; gf.oF = (float*)d_out;
  gemm9<2, 128, false><<<gf.nwg, 512, 0, stream>>>(gf);
}